// Round 16
// baseline (180.146 us; speedup 1.0000x reference)
//
#include <hip/hip_runtime.h>

#define N_NODES 50000
#define N_EDGES 800000
#define F 64
#define CHUNK 6144       // edges per partition workgroup
#define NWG1 ((N_EDGES + CHUNK - 1) / CHUNK)   // 131
#define NBUCK 196        // coarse buckets: dst >> 8
#define BSTRIDE 8192     // fixed per-bucket capacity (mean 4082, sigma ~64)
#define NWTILE (N_NODES / 16)   // 3125 exact

typedef __attribute__((ext_vector_type(8))) _Float16 half8;   // 16 B
typedef __attribute__((ext_vector_type(4))) _Float16 half4;   // 8 B
typedef __attribute__((ext_vector_type(4))) float f32x4;

// ---------- K1: partition into fixed-capacity buckets + f16 convert + W prep ----
// (R14 proven) Features written as SPLIT tables xlo/xhi (3.2 MB each) so a
// gather pass's working set fits the 4 MiB per-XCD L2.
__global__ __launch_bounds__(256) void partition_conv(
    const int*    __restrict__ src, const int* __restrict__ dst,
    const float4* __restrict__ xin,      // [N*16] float4 view of x
    half8*        __restrict__ xlo8,     // [N*4] half8s: features 0..31
    half8*        __restrict__ xhi8,     // [N*4] half8s: features 32..63
    const float*  __restrict__ W1, const float* __restrict__ W2,
    _Float16*     __restrict__ Wt1, _Float16* __restrict__ Wt2,
    unsigned*     __restrict__ bcur,     // [256] zeroed cursors
    unsigned*     __restrict__ ebuf) {   // [NBUCK*BSTRIDE] strided buckets
  int t = threadIdx.x, b = blockIdx.x;
  if (b == NWG1) {                       // W prep block
    for (int i = t; i < 64 * 128; i += 256) {
      int n = i >> 7, k = i & 127;       // Wt[n][k] = W[k][n]
      Wt1[i] = (_Float16)W1[k * 64 + n];
      Wt2[i] = (_Float16)W2[k * 64 + n];
    }
    return;
  }
  __shared__ int hist[256], lscan[256], lcur[256], gbase[256];
  __shared__ unsigned stage[CHUNK];      // 24 KB
  hist[t] = 0; __syncthreads();
  int e0 = b * CHUNK;
  int cnt = N_EDGES - e0; if (cnt > CHUNK) cnt = CHUNK;
  for (int i = t; i < cnt; i += 256) atomicAdd(&hist[dst[e0 + i] >> 8], 1);

  // f32 -> f16 conversion into split tables, grid-stride
  const int TOT = N_NODES * F / 8;       // 400000 half8s
  for (int i = b * 256 + t; i < TOT; i += NWG1 * 256) {
    float4 a = xin[i * 2], c = xin[i * 2 + 1];
    half8 hh;
    hh[0] = (_Float16)a.x; hh[1] = (_Float16)a.y;
    hh[2] = (_Float16)a.z; hh[3] = (_Float16)a.w;
    hh[4] = (_Float16)c.x; hh[5] = (_Float16)c.y;
    hh[6] = (_Float16)c.z; hh[7] = (_Float16)c.w;
    int node = i >> 3, part = i & 7;     // part = which half8 of the 64-feat row
    if (part < 4) xlo8[node * 4 + part]       = hh;
    else          xhi8[node * 4 + (part - 4)] = hh;
  }
  __syncthreads();

  int v = hist[t];
  lscan[t] = v; __syncthreads();
  for (int off = 1; off < 256; off <<= 1) {
    int a = (t >= off) ? lscan[t - off] : 0;
    __syncthreads();
    lscan[t] += a;
    __syncthreads();
  }
  lscan[t] -= v;
  lcur[t] = lscan[t];
  if (v > 0) gbase[t] = (int)atomicAdd(&bcur[t], (unsigned)v);
  __syncthreads();

  for (int i = t; i < cnt; i += 256) {
    int d = dst[e0 + i], s = src[e0 + i];
    int bb = d >> 8;
    int p = atomicAdd(&lcur[bb], 1);
    stage[p] = ((unsigned)bb << 24) | ((unsigned)(d & 255) << 16) | (unsigned)s;
  }
  __syncthreads();
  for (int i = t; i < cnt; i += 256) {
    unsigned e = stage[i];
    int bb = e >> 24;
    ebuf[bb * BSTRIDE + gbase[bb] + (i - lscan[bb])] = e;
  }
}

// ---------- K2: per-bucket counting sort (R14 proven) ----------
__global__ __launch_bounds__(256) void bucket_sort(
    const unsigned* __restrict__ ebuf, const unsigned* __restrict__ bcur,
    unsigned short* __restrict__ edge_src, int* __restrict__ row_start,
    int* __restrict__ deg) {
  __shared__ int lhist[256], lscan[256], lcur[256];
  __shared__ unsigned short srt[BSTRIDE];    // 16 KB
  int b = blockIdx.x, t = threadIdx.x;
  int s0 = b * BSTRIDE;
  int cnt = (int)bcur[b];

  lhist[t] = 0; __syncthreads();
  for (int i = t; i < cnt; i += 256) atomicAdd(&lhist[(ebuf[s0 + i] >> 16) & 255], 1);
  __syncthreads();

  int v = lhist[t];
  lscan[t] = v; __syncthreads();
  for (int off = 1; off < 256; off <<= 1) {
    int a = (t >= off) ? lscan[t - off] : 0;
    __syncthreads();
    lscan[t] += a;
    __syncthreads();
  }
  lscan[t] -= v;
  lcur[t] = lscan[t];
  __syncthreads();

  for (int i = t; i < cnt; i += 256) {
    unsigned e = ebuf[s0 + i];
    int p = atomicAdd(&lcur[(e >> 16) & 255], 1);
    srt[p] = (unsigned short)(e & 0xFFFFu);
  }
  __syncthreads();

  for (int i = t; i < cnt; i += 256) edge_src[s0 + i] = srt[i];

  int n = b * 256 + t;
  if (n < N_NODES) { row_start[n] = s0 + lscan[t]; deg[n] = v; }
}

// ---------- fused layer: split-table L2-resident gather -> LDS -> MFMA ----------
// Block = 4 waves = 32 nodes = 2 MFMA tiles.
// Phase 1: octet o owns node blk*32+w*8+o; lane q in 0..7 owns 4 features (8 B).
//   TWO sequential passes over the edge list (lo table then hi table): per-pass
//   working set 3.2 MB -> per-XCD-L2 resident. Packed f16 accumulation
//   (half4 += -> v_pk_add_f16), no cross-lane fold, 8 loads in flight.
// Phase 2 (R10/R13 proven MFMA): A-frags k0..31 from lo, k32..63 from hi.
__global__ __launch_bounds__(256) void sage_layer_fused(
    const half4*    __restrict__ glo,       // [N*8] gather lo (features 0..31)
    const half4*    __restrict__ ghi,       // [N*8] gather hi (features 32..63)
    const _Float16* __restrict__ slo,       // [N*32] self lo
    const _Float16* __restrict__ shi,       // [N*32] self hi
    const int*      __restrict__ row_start,
    const int*      __restrict__ deg,
    const unsigned short* __restrict__ edge_src,
    const _Float16* __restrict__ Wt,        // [64,128]  Wt[n][k] = W[k][n]
    const float*    __restrict__ bias,      // [64]
    float*          __restrict__ outf,      // [N,64] f32 or null
    unsigned short* __restrict__ o16lo,     // [N*32] f16 lo or null
    unsigned short* __restrict__ o16hi,     // [N*32] f16 hi or null
    int do_relu) {
  __shared__ _Float16 lmean[32 * 72];       // node stride 72 halves, 4.6 KB
  int t = threadIdx.x;
  int w = t >> 6, lane = t & 63;

  // ---- phase 1 ----
  {
    int o = lane >> 3, q = lane & 7;
    int n = blockIdx.x * 32 + w * 8 + o;
    if (n < N_NODES) {
      int start = row_start[n];
      int d     = deg[n];
      half4 aclo = (half4){0, 0, 0, 0};
      half4 achi = (half4){0, 0, 0, 0};
      // pass A: lo table (3.2 MB working set)
      for (int base = 0; base < d; base += 8) {
        #pragma unroll
        for (int uu = 0; uu < 8; ++uu) {
          int e = base + uu;
          if (e < d) {
            int s = (int)edge_src[start + e];
            aclo += glo[(size_t)s * 8 + q];          // 8 B, L2-hit
          }
        }
      }
      // pass B: hi table
      for (int base = 0; base < d; base += 8) {
        #pragma unroll
        for (int uu = 0; uu < 8; ++uu) {
          int e = base + uu;
          if (e < d) {
            int s = (int)edge_src[start + e];
            achi += ghi[(size_t)s * 8 + q];
          }
        }
      }
      float inv = (d > 0) ? 1.0f / (float)d : 0.0f;
      half4 mlo, mhi;
      #pragma unroll
      for (int k = 0; k < 4; ++k) {
        mlo[k] = (_Float16)((float)aclo[k] * inv);
        mhi[k] = (_Float16)((float)achi[k] * inv);
      }
      int ln = w * 8 + o;
      *(half4*)&lmean[ln * 72 + q * 4]      = mlo;   // mean features q*4..q*4+3
      *(half4*)&lmean[ln * 72 + 32 + q * 4] = mhi;   // mean features 32+q*4..
    }
  }
  __syncthreads();

  // ---- phase 2: MFMA; wave w does nt-half (w&1) of tile (w>>1) ----
  int tile = w >> 1;
  int wt = blockIdx.x * 2 + tile;
  if (wt >= NWTILE) return;
  int m = lane & 15, quad = lane >> 4;
  size_t srow = (size_t)(wt * 16 + m) * 32 + quad * 8;
  half8 a0 = *(const half8*)(slo + srow);            // k 0..31  (self lo)
  half8 a1 = *(const half8*)(shi + srow);            // k 32..63 (self hi)
  int ln = tile * 16 + m;
  half8 a2 = *(const half8*)&lmean[ln * 72 + quad * 8];        // k 64..95
  half8 a3 = *(const half8*)&lmean[ln * 72 + 32 + quad * 8];   // k 96..127

  int nt0 = (w & 1) * 2;
  #pragma unroll
  for (int i = 0; i < 2; ++i) {
    int nt = nt0 + i;
    float bv = bias[nt * 16 + m];
    f32x4 acc = (f32x4){bv, bv, bv, bv};
    const _Float16* wrow = Wt + (size_t)(nt * 16 + m) * 128 + quad * 8;
    half8 b0 = *(const half8*)(wrow);
    half8 b1 = *(const half8*)(wrow + 32);
    half8 b2 = *(const half8*)(wrow + 64);
    half8 b3 = *(const half8*)(wrow + 96);
    acc = __builtin_amdgcn_mfma_f32_16x16x32_f16(a0, b0, acc, 0, 0, 0);
    acc = __builtin_amdgcn_mfma_f32_16x16x32_f16(a1, b1, acc, 0, 0, 0);
    acc = __builtin_amdgcn_mfma_f32_16x16x32_f16(a2, b2, acc, 0, 0, 0);
    acc = __builtin_amdgcn_mfma_f32_16x16x32_f16(a3, b3, acc, 0, 0, 0);
    #pragma unroll
    for (int r = 0; r < 4; ++r) {
      size_t row = (size_t)(wt * 16 + quad * 4 + r);
      int col = nt * 16 + m;
      float v = acc[r];
      if (do_relu) v = fmaxf(v, 0.0f);
      if (outf) outf[row * 64 + col] = v;
      if (o16lo) {
        _Float16 hv = (_Float16)v;
        unsigned short us = *(unsigned short*)&hv;
        if (nt < 2) o16lo[row * 32 + col] = us;
        else        o16hi[row * 32 + (col - 32)] = us;
      }
    }
  }
}

extern "C" void kernel_launch(void* const* d_in, const int* in_sizes, int n_in,
                              void* d_out, int out_size, void* d_ws, size_t ws_size,
                              hipStream_t stream) {
  const float* x  = (const float*)d_in[0];
  const int*   ei = (const int*)d_in[1];   // [2,E]: row 0 = src, row 1 = dst
  const float* W1 = (const float*)d_in[2];
  const float* b1 = (const float*)d_in[3];
  const float* W2 = (const float*)d_in[4];
  const float* b2 = (const float*)d_in[5];
  float* out = (float*)d_out;

  const int* src = ei;
  const int* dst = ei + N_EDGES;

  // ws layout (int offsets), all 16B-aligned. Each split f16 table is
  // [N*32] halves = 1.6M halves = 800,000 ints (R15's bug: had 400,000).
  //   bcur@0[256] | deg@256[50048] | row_start@50304[50048] |
  //   edge_src@100352[802816] | ebuf@903168[1605632] |
  //   xlo@2508800[800000] | xhi@3308800[800000] |
  //   h1lo@4108800[800000] | h1hi@4908800[800000] |
  //   Wt1@5708800[4096] | Wt2@5712896[4096]   total 5,716,992 ints = 22.9 MB
  int* wsi       = (int*)d_ws;
  unsigned* bcur = (unsigned*)wsi;
  int* deg       = wsi + 256;
  int* row_start = wsi + 50304;
  unsigned short* edge_src = (unsigned short*)(wsi + 100352);
  unsigned* ebuf = (unsigned*)(wsi + 903168);
  _Float16* xlo  = (_Float16*)(wsi + 2508800);
  _Float16* xhi  = (_Float16*)(wsi + 3308800);
  _Float16* h1lo = (_Float16*)(wsi + 4108800);
  _Float16* h1hi = (_Float16*)(wsi + 4908800);
  _Float16* Wt1  = (_Float16*)(wsi + 5708800);
  _Float16* Wt2  = (_Float16*)(wsi + 5712896);

  hipMemsetAsync(bcur, 0, 256 * sizeof(unsigned), stream);

  dim3 blk(256);
  partition_conv<<<NWG1 + 1, blk, 0, stream>>>(
      src, dst, (const float4*)x, (half8*)xlo, (half8*)xhi,
      W1, W2, Wt1, Wt2, bcur, ebuf);
  bucket_sort<<<NBUCK, blk, 0, stream>>>(ebuf, bcur, edge_src, row_start, deg);

  dim3 grd_fused((N_NODES + 31) / 32);   // 1563 blocks = 3126 tiles >= 3125

  // Layer 1: h1 = relu([x||mean]W1+b1), emitted as split f16 tables
  sage_layer_fused<<<grd_fused, blk, 0, stream>>>(
      (const half4*)xlo, (const half4*)xhi, xlo, xhi,
      row_start, deg, edge_src, Wt1, b1,
      nullptr, (unsigned short*)h1lo, (unsigned short*)h1hi, 1);
  // Layer 2: out = [h1||mean]W2+b2 (f32)
  sage_layer_fused<<<grd_fused, blk, 0, stream>>>(
      (const half4*)h1lo, (const half4*)h1hi, h1lo, h1hi,
      row_start, deg, edge_src, Wt2, b2,
      out, nullptr, nullptr, 0);
}

// Round 17
// 158.985 us; speedup vs baseline: 1.1331x; 1.1331x over previous
//
#include <hip/hip_runtime.h>

#define N_NODES 50000
#define N_EDGES 800000
#define F 64
#define CHUNK 6144       // edges per partition workgroup
#define NWG1 ((N_EDGES + CHUNK - 1) / CHUNK)   // 131
#define NBUCK 196        // coarse buckets: dst >> 8
#define BSTRIDE 8192     // fixed per-bucket capacity (mean 4082, sigma ~64)
#define NWTILE (N_NODES / 16)   // 3125 exact

typedef __attribute__((ext_vector_type(8))) _Float16 half8;   // 16 B
typedef __attribute__((ext_vector_type(4))) float f32x4;

// ---------- K1: partition into fixed-capacity buckets + f16 convert + W prep ----
// (R14 proven) Single unified f16 feature table x16 [N,64].
__global__ __launch_bounds__(256) void partition_conv(
    const int*    __restrict__ src, const int* __restrict__ dst,
    const float4* __restrict__ xin,      // [N*16] float4 view of x
    half8*        __restrict__ x16,      // [N*8] f16 rows
    const float*  __restrict__ W1, const float* __restrict__ W2,
    _Float16*     __restrict__ Wt1, _Float16* __restrict__ Wt2,
    unsigned*     __restrict__ bcur,     // [256] zeroed cursors
    unsigned*     __restrict__ ebuf) {   // [NBUCK*BSTRIDE] strided buckets
  int t = threadIdx.x, b = blockIdx.x;
  if (b == NWG1) {                       // W prep block
    for (int i = t; i < 64 * 128; i += 256) {
      int n = i >> 7, k = i & 127;       // Wt[n][k] = W[k][n]
      Wt1[i] = (_Float16)W1[k * 64 + n];
      Wt2[i] = (_Float16)W2[k * 64 + n];
    }
    return;
  }
  __shared__ int hist[256], lscan[256], lcur[256], gbase[256];
  __shared__ unsigned stage[CHUNK];      // 24 KB
  hist[t] = 0; __syncthreads();
  int e0 = b * CHUNK;
  int cnt = N_EDGES - e0; if (cnt > CHUNK) cnt = CHUNK;
  for (int i = t; i < cnt; i += 256) atomicAdd(&hist[dst[e0 + i] >> 8], 1);

  // f32 -> f16 feature conversion, grid-stride
  const int TOT = N_NODES * F / 8;
  for (int i = b * 256 + t; i < TOT; i += NWG1 * 256) {
    float4 a = xin[i * 2], c = xin[i * 2 + 1];
    half8 hh;
    hh[0] = (_Float16)a.x; hh[1] = (_Float16)a.y;
    hh[2] = (_Float16)a.z; hh[3] = (_Float16)a.w;
    hh[4] = (_Float16)c.x; hh[5] = (_Float16)c.y;
    hh[6] = (_Float16)c.z; hh[7] = (_Float16)c.w;
    x16[i] = hh;
  }
  __syncthreads();

  int v = hist[t];
  lscan[t] = v; __syncthreads();
  for (int off = 1; off < 256; off <<= 1) {
    int a = (t >= off) ? lscan[t - off] : 0;
    __syncthreads();
    lscan[t] += a;
    __syncthreads();
  }
  lscan[t] -= v;                         // exclusive local scan
  lcur[t] = lscan[t];
  if (v > 0) gbase[t] = (int)atomicAdd(&bcur[t], (unsigned)v);  // in-bucket base
  __syncthreads();

  for (int i = t; i < cnt; i += 256) {
    int d = dst[e0 + i], s = src[e0 + i];
    int bb = d >> 8;
    int p = atomicAdd(&lcur[bb], 1);
    stage[p] = ((unsigned)bb << 24) | ((unsigned)(d & 255) << 16) | (unsigned)s;
  }
  __syncthreads();
  for (int i = t; i < cnt; i += 256) {
    unsigned e = stage[i];
    int bb = e >> 24;
    ebuf[bb * BSTRIDE + gbase[bb] + (i - lscan[bb])] = e;   // coalesced runs
  }
}

// ---------- K2: per-bucket counting sort (R14 proven) ----------
__global__ __launch_bounds__(256) void bucket_sort(
    const unsigned* __restrict__ ebuf, const unsigned* __restrict__ bcur,
    unsigned short* __restrict__ edge_src, int* __restrict__ row_start,
    int* __restrict__ deg) {
  __shared__ int lhist[256], lscan[256], lcur[256];
  __shared__ unsigned short srt[BSTRIDE];    // 16 KB
  int b = blockIdx.x, t = threadIdx.x;
  int s0 = b * BSTRIDE;
  int cnt = (int)bcur[b];

  lhist[t] = 0; __syncthreads();
  for (int i = t; i < cnt; i += 256) atomicAdd(&lhist[(ebuf[s0 + i] >> 16) & 255], 1);
  __syncthreads();

  int v = lhist[t];
  lscan[t] = v; __syncthreads();
  for (int off = 1; off < 256; off <<= 1) {
    int a = (t >= off) ? lscan[t - off] : 0;
    __syncthreads();
    lscan[t] += a;
    __syncthreads();
  }
  lscan[t] -= v;
  lcur[t] = lscan[t];
  __syncthreads();

  for (int i = t; i < cnt; i += 256) {
    unsigned e = ebuf[s0 + i];
    int p = atomicAdd(&lcur[(e >> 16) & 255], 1);
    srt[p] = (unsigned short)(e & 0xFFFFu);
  }
  __syncthreads();

  for (int i = t; i < cnt; i += 256) edge_src[s0 + i] = srt[i];   // coalesced 2B

  int n = b * 256 + t;
  if (n < N_NODES) { row_start[n] = s0 + lscan[t]; deg[n] = v; }
}

// ---------- fused layer: octet-per-node aggregate -> LDS -> MFMA linear ----------
// (R13/R14 proven structure) Block = 4 waves = 32 nodes = 2 MFMA tiles.
// Phase 1: octet o owns node blk*32+w*8+o; lane q holds feature octet q (16 B);
//   single pass, 8 gathers in flight; PACKED f16 accumulation (half8 += half8 ->
//   4x v_pk_add_f16, accuracy HW-validated in R16: absmax identical to f32 accum).
// Phase 2: MFMA linear; wave w does nt-half (w&1) of tile (w>>1).
__global__ __launch_bounds__(256) void sage_layer_fused(
    const half8*    __restrict__ feat16,    // [N,8] gather source (= self16)
    const _Float16* __restrict__ self16,    // [N,64]
    const int*      __restrict__ row_start,
    const int*      __restrict__ deg,
    const unsigned short* __restrict__ edge_src,
    const _Float16* __restrict__ Wt,        // [64,128]  Wt[n][k] = W[k][n]
    const float*    __restrict__ bias,      // [64]
    float*          __restrict__ outf,      // [N,64] f32 or null
    unsigned short* __restrict__ out16,     // [N,64] f16 or null
    int do_relu) {
  __shared__ _Float16 lmean[32 * 72];       // node stride 72 halves, 4.6 KB
  int t = threadIdx.x;
  int w = t >> 6, lane = t & 63;

  // ---- phase 1: aggregate 8 nodes per wave (octet-per-node, packed f16) ----
  {
    int o = lane >> 3, q = lane & 7;
    int n = blockIdx.x * 32 + w * 8 + o;
    if (n < N_NODES) {
      int start = row_start[n];
      int d     = deg[n];
      half8 acc8 = (half8){0, 0, 0, 0, 0, 0, 0, 0};
      for (int base = 0; base < d; base += 8) {
        #pragma unroll
        for (int uu = 0; uu < 8; ++uu) {
          int e = base + uu;
          if (e < d) {
            int s = (int)edge_src[start + e];        // broadcast within octet
            acc8 += feat16[(size_t)s * 8 + q];       // 128 B row; v_pk_add_f16
          }
        }
      }
      float inv = (d > 0) ? 1.0f / (float)d : 0.0f;
      half8 h;
      #pragma unroll
      for (int k = 0; k < 8; ++k) h[k] = (_Float16)((float)acc8[k] * inv);
      *(half8*)&lmean[(w * 8 + o) * 72 + q * 8] = h;
    }
  }
  __syncthreads();

  // ---- phase 2: MFMA linear; wave w does nt-half (w&1) of tile (w>>1) ----
  int tile = w >> 1;
  int wt = blockIdx.x * 2 + tile;
  if (wt >= NWTILE) return;
  int m = lane & 15, quad = lane >> 4;
  size_t arow = (size_t)(wt * 16 + m) * 64 + quad * 8;
  half8 a0 = *(const half8*)(self16 + arow);
  half8 a1 = *(const half8*)(self16 + arow + 32);
  int ln = tile * 16 + m;                   // local node 0..31
  half8 a2 = *(const half8*)&lmean[ln * 72 + quad * 8];
  half8 a3 = *(const half8*)&lmean[ln * 72 + quad * 8 + 32];

  int nt0 = (w & 1) * 2;                    // 0 or 2
  #pragma unroll
  for (int i = 0; i < 2; ++i) {
    int nt = nt0 + i;
    float bv = bias[nt * 16 + m];           // col = lane&15
    f32x4 acc = (f32x4){bv, bv, bv, bv};
    const _Float16* wrow = Wt + (size_t)(nt * 16 + m) * 128 + quad * 8;
    half8 b0 = *(const half8*)(wrow);
    half8 b1 = *(const half8*)(wrow + 32);
    half8 b2 = *(const half8*)(wrow + 64);
    half8 b3 = *(const half8*)(wrow + 96);
    acc = __builtin_amdgcn_mfma_f32_16x16x32_f16(a0, b0, acc, 0, 0, 0);
    acc = __builtin_amdgcn_mfma_f32_16x16x32_f16(a1, b1, acc, 0, 0, 0);
    acc = __builtin_amdgcn_mfma_f32_16x16x32_f16(a2, b2, acc, 0, 0, 0);
    acc = __builtin_amdgcn_mfma_f32_16x16x32_f16(a3, b3, acc, 0, 0, 0);
    #pragma unroll
    for (int r = 0; r < 4; ++r) {
      size_t off = (size_t)(wt * 16 + quad * 4 + r) * 64 + nt * 16 + m;
      float v = acc[r];
      if (do_relu) v = fmaxf(v, 0.0f);
      if (outf)  outf[off] = v;
      if (out16) { _Float16 hv = (_Float16)v; out16[off] = *(unsigned short*)&hv; }
    }
  }
}

extern "C" void kernel_launch(void* const* d_in, const int* in_sizes, int n_in,
                              void* d_out, int out_size, void* d_ws, size_t ws_size,
                              hipStream_t stream) {
  const float* x  = (const float*)d_in[0];
  const int*   ei = (const int*)d_in[1];   // [2,E]: row 0 = src, row 1 = dst
  const float* W1 = (const float*)d_in[2];
  const float* b1 = (const float*)d_in[3];
  const float* W2 = (const float*)d_in[4];
  const float* b2 = (const float*)d_in[5];
  float* out = (float*)d_out;

  const int* src = ei;
  const int* dst = ei + N_EDGES;

  // ws layout (int offsets), all 16B-aligned (R14 proven):
  //   bcur@0[256] | deg@256[50048] | row_start@50304[50048] |
  //   edge_src@100352[196*8192 ushorts = 802816 ints] | ebuf@903168[1605632] |
  //   x16@2508800[1600000] | h116@4108800[1600000] |
  //   Wt1@5708800[4096] | Wt2@5712896[4096]   total 5,716,992 ints = 22.9 MB
  int* wsi       = (int*)d_ws;
  unsigned* bcur = (unsigned*)wsi;
  int* deg       = wsi + 256;
  int* row_start = wsi + 50304;
  unsigned short* edge_src = (unsigned short*)(wsi + 100352);
  unsigned* ebuf = (unsigned*)(wsi + 903168);
  half8* x16     = (half8*)(wsi + 2508800);
  unsigned short* h116 = (unsigned short*)(wsi + 4108800);
  _Float16* Wt1  = (_Float16*)(wsi + 5708800);
  _Float16* Wt2  = (_Float16*)(wsi + 5712896);

  hipMemsetAsync(bcur, 0, 256 * sizeof(unsigned), stream);

  dim3 blk(256);
  partition_conv<<<NWG1 + 1, blk, 0, stream>>>(
      src, dst, (const float4*)x, x16, W1, W2, Wt1, Wt2, bcur, ebuf);
  bucket_sort<<<NBUCK, blk, 0, stream>>>(ebuf, bcur, edge_src, row_start, deg);

  dim3 grd_fused((N_NODES + 31) / 32);   // 1563 blocks = 3126 tiles >= 3125

  // Layer 1: h1 = relu([x||mean]W1+b1), kept only as f16
  sage_layer_fused<<<grd_fused, blk, 0, stream>>>(
      x16, (const _Float16*)x16, row_start, deg, edge_src,
      Wt1, b1, nullptr, h116, 1);
  // Layer 2: out = [h1||mean]W2+b2 (f32)
  sage_layer_fused<<<grd_fused, blk, 0, stream>>>(
      (const half8*)h116, (const _Float16*)h116, row_start, deg, edge_src,
      Wt2, b2, out, nullptr, 0);
}